// Round 1
// baseline (479.919 us; speedup 1.0000x reference)
//
#include <hip/hip_runtime.h>
#include <math.h>

#define KCODES 512
#define DIM 64
#define NROWS (64 * 4096)          // B*S
#define BLOCK 256
#define NBLOCKS (NROWS / BLOCK)    // 1024

// ---------------------------------------------------------------------------
// Kernel A: precompute ||e_k||^2 for all K codes into ws.
// ---------------------------------------------------------------------------
__global__ void vq_enorm_kernel(const float* __restrict__ emb,
                                float* __restrict__ enorm) {
    int k = blockIdx.x * blockDim.x + threadIdx.x;
    if (k < KCODES) {
        const float4* e4 = reinterpret_cast<const float4*>(emb + k * DIM);
        float s0 = 0.f, s1 = 0.f, s2 = 0.f, s3 = 0.f;
#pragma unroll
        for (int i = 0; i < DIM / 4; ++i) {
            float4 v = e4[i];
            s0 = fmaf(v.x, v.x, s0);
            s1 = fmaf(v.y, v.y, s1);
            s2 = fmaf(v.z, v.z, s2);
            s3 = fmaf(v.w, v.w, s3);
        }
        enorm[k] = (s0 + s1) + (s2 + s3);
    }
}

// ---------------------------------------------------------------------------
// Kernel B: main VQ. One thread per row (D=64 in registers).
//   score_k = ||e_k||^2 - 2 * x . e_k   (||x||^2 dropped: row-constant)
//   strict < keeps the FIRST minimum -> matches np.argmin tie rule.
// Writes quantized row + per-block loss partial (sum of (q-x)^2).
// ---------------------------------------------------------------------------
__launch_bounds__(BLOCK, 4)
__global__ void vq_main_kernel(const float* __restrict__ lat,
                               const float* __restrict__ emb,
                               const float* __restrict__ enorm,
                               float* __restrict__ outq,
                               float* __restrict__ partials) {
    const int row = blockIdx.x * BLOCK + threadIdx.x;

    // Load this row into registers (16 x float4).
    float x[DIM];
    const float4* xin = reinterpret_cast<const float4*>(lat + (size_t)row * DIM);
#pragma unroll
    for (int i = 0; i < DIM / 4; ++i) {
        float4 v = xin[i];
        x[4 * i + 0] = v.x;
        x[4 * i + 1] = v.y;
        x[4 * i + 2] = v.z;
        x[4 * i + 3] = v.w;
    }

    float best = INFINITY;
    int bestk = 0;
    for (int k = 0; k < KCODES; ++k) {
        // k is wave-uniform -> these loads should become scalar (SMEM) loads.
        const float4* e4 = reinterpret_cast<const float4*>(emb + k * DIM);
        float a0 = 0.f, a1 = 0.f, a2 = 0.f, a3 = 0.f;
#pragma unroll
        for (int i = 0; i < DIM / 4; ++i) {
            float4 v = e4[i];
            a0 = fmaf(x[4 * i + 0], v.x, a0);
            a1 = fmaf(x[4 * i + 1], v.y, a1);
            a2 = fmaf(x[4 * i + 2], v.z, a2);
            a3 = fmaf(x[4 * i + 3], v.w, a3);
        }
        float dot = (a0 + a1) + (a2 + a3);
        float s = fmaf(-2.f, dot, enorm[k]);
        if (s < best) { best = s; bestk = k; }
    }

    // Gather chosen code, write quantized row, accumulate squared error.
    float lsum = 0.f;
    float4* outv = reinterpret_cast<float4*>(outq + (size_t)row * DIM);
    const float4* eb = reinterpret_cast<const float4*>(emb + bestk * DIM);
#pragma unroll
    for (int i = 0; i < DIM / 4; ++i) {
        float4 v = eb[i];
        outv[i] = v;
        float d0 = v.x - x[4 * i + 0];
        float d1 = v.y - x[4 * i + 1];
        float d2 = v.z - x[4 * i + 2];
        float d3 = v.w - x[4 * i + 3];
        lsum = fmaf(d0, d0, lsum);
        lsum = fmaf(d1, d1, lsum);
        lsum = fmaf(d2, d2, lsum);
        lsum = fmaf(d3, d3, lsum);
    }

    // Block-reduce lsum (deterministic): wave shuffle then LDS.
#pragma unroll
    for (int off = 32; off > 0; off >>= 1)
        lsum += __shfl_down(lsum, off, 64);
    __shared__ float wsum[BLOCK / 64];
    const int lane = threadIdx.x & 63;
    const int wid = threadIdx.x >> 6;
    if (lane == 0) wsum[wid] = lsum;
    __syncthreads();
    if (threadIdx.x == 0) {
        float t = 0.f;
#pragma unroll
        for (int w = 0; w < BLOCK / 64; ++w) t += wsum[w];
        partials[blockIdx.x] = t;
    }
}

// ---------------------------------------------------------------------------
// Kernel C: reduce the NBLOCKS partials -> vq_loss scalar.
//   vq_loss = (1 + BETA) * mean((q - x)^2), BETA = 0.25
// ---------------------------------------------------------------------------
__global__ void vq_loss_kernel(const float* __restrict__ partials,
                               float* __restrict__ loss) {
    float s = 0.f;
    for (int i = threadIdx.x; i < NBLOCKS; i += BLOCK) s += partials[i];
#pragma unroll
    for (int off = 32; off > 0; off >>= 1)
        s += __shfl_down(s, off, 64);
    __shared__ float wsum[BLOCK / 64];
    const int lane = threadIdx.x & 63;
    const int wid = threadIdx.x >> 6;
    if (lane == 0) wsum[wid] = s;
    __syncthreads();
    if (threadIdx.x == 0) {
        float t = 0.f;
#pragma unroll
        for (int w = 0; w < BLOCK / 64; ++w) t += wsum[w];
        loss[0] = 1.25f * (t / (float)((size_t)NROWS * DIM));
    }
}

// ---------------------------------------------------------------------------
extern "C" void kernel_launch(void* const* d_in, const int* in_sizes, int n_in,
                              void* d_out, int out_size, void* d_ws, size_t ws_size,
                              hipStream_t stream) {
    const float* lat = (const float*)d_in[0];   // [B,S,D] fp32
    const float* emb = (const float*)d_in[1];   // [K,D]   fp32
    float* outq = (float*)d_out;                // output 0: quantized [B,S,D]
    float* loss = (float*)d_out + (size_t)NROWS * DIM;  // output 1: scalar

    float* enorm    = (float*)d_ws;             // [K]
    float* partials = (float*)d_ws + KCODES;    // [NBLOCKS]

    vq_enorm_kernel<<<(KCODES + 255) / 256, 256, 0, stream>>>(emb, enorm);
    vq_main_kernel<<<NBLOCKS, BLOCK, 0, stream>>>(lat, emb, enorm, outq, partials);
    vq_loss_kernel<<<1, BLOCK, 0, stream>>>(partials, loss);
}

// Round 2
// 63.088 us; speedup vs baseline: 7.6072x; 7.6072x over previous
//
#include <hip/hip_runtime.h>
#include <math.h>

#define KCODES 512
#define DIM 64
#define NROWS (64 * 4096)     // B*S = 262144
#define BM 128                // rows per block
#define BLOCK 256             // 4 waves
#define NBLK (NROWS / BM)     // 2048

typedef __bf16 bf16x8 __attribute__((ext_vector_type(8)));
typedef float f32x4 __attribute__((ext_vector_type(4)));

// ---------------------------------------------------------------------------
// Kernel A: ||e_k||^2 in fp32 (exact embedding, not bf16).
// ---------------------------------------------------------------------------
__global__ void vq_enorm_kernel(const float* __restrict__ emb,
                                float* __restrict__ enorm) {
    int k = blockIdx.x * blockDim.x + threadIdx.x;
    if (k < KCODES) {
        const float4* e4 = reinterpret_cast<const float4*>(emb + k * DIM);
        float s0 = 0.f, s1 = 0.f, s2 = 0.f, s3 = 0.f;
#pragma unroll
        for (int i = 0; i < DIM / 4; ++i) {
            float4 v = e4[i];
            s0 = fmaf(v.x, v.x, s0);
            s1 = fmaf(v.y, v.y, s1);
            s2 = fmaf(v.z, v.z, s2);
            s3 = fmaf(v.w, v.w, s3);
        }
        enorm[k] = (s0 + s1) + (s2 + s3);
    }
}

// ---------------------------------------------------------------------------
// Kernel B: MFMA scoring + argmin + gather + loss partial.
//   scores[m][n] = enorm[n] - 2 * x_m . e_n   (bf16 MFMA, fp32 accum)
//   A-frag: lane holds X[m = l&15][k = 32*ks + 8*(l>>4) + b]
//   B-frag: lane holds E[n = l&15][k = 32*ks + 8*(l>>4) + b]
//   C/D:    col(n) = l&15, row(m) = (l>>4)*4 + r   [measured m89/m91]
// E tile in LDS, XOR-swizzled in 16B chunks: chunk' = chunk ^ (row&7).
// ---------------------------------------------------------------------------
__launch_bounds__(BLOCK, 2)
__global__ void vq_mfma_kernel(const float* __restrict__ lat,
                               const float* __restrict__ emb,
                               const float* __restrict__ enorm,
                               float* __restrict__ outq,
                               float* __restrict__ partials) {
    __shared__ __align__(16) __bf16 e_lds[KCODES * DIM];  // 64 KB, swizzled
    __shared__ float en_lds[KCODES];
    __shared__ int bestk_lds[BM];
    __shared__ float wsum_lds[BLOCK / 64];

    const int t = threadIdx.x;
    const int lane = t & 63, wid = t >> 6;
    const int l15 = lane & 15, lq = lane >> 4;
    const size_t blockrow = (size_t)blockIdx.x * BM;

    // ---- A fragments: direct global->reg (independent of LDS, issue early)
    bf16x8 afrag[2][2];
#pragma unroll
    for (int mf = 0; mf < 2; ++mf) {
#pragma unroll
        for (int ks = 0; ks < 2; ++ks) {
            const float* xp =
                lat + (blockrow + wid * 32 + mf * 16 + l15) * DIM + ks * 32 + lq * 8;
            float4 v0 = reinterpret_cast<const float4*>(xp)[0];
            float4 v1 = reinterpret_cast<const float4*>(xp)[1];
            bf16x8 a;
            a[0] = (__bf16)v0.x; a[1] = (__bf16)v0.y;
            a[2] = (__bf16)v0.z; a[3] = (__bf16)v0.w;
            a[4] = (__bf16)v1.x; a[5] = (__bf16)v1.y;
            a[6] = (__bf16)v1.z; a[7] = (__bf16)v1.w;
            afrag[mf][ks] = a;
        }
    }

    // ---- stage E: fp32 global -> bf16 LDS, swizzled 16B chunks, coalesced
    // 4096 chunks of 8 elems; 16 per thread.
#pragma unroll
    for (int i = 0; i < 16; ++i) {
        int c8 = t + i * BLOCK;           // 8-elem chunk id
        int row = c8 >> 3;                // code index
        int ch = (c8 & 7) ^ (row & 7);    // swizzled chunk-in-row
        float4 v0 = reinterpret_cast<const float4*>(emb)[c8 * 2];
        float4 v1 = reinterpret_cast<const float4*>(emb)[c8 * 2 + 1];
        bf16x8 p;
        p[0] = (__bf16)v0.x; p[1] = (__bf16)v0.y;
        p[2] = (__bf16)v0.z; p[3] = (__bf16)v0.w;
        p[4] = (__bf16)v1.x; p[5] = (__bf16)v1.y;
        p[6] = (__bf16)v1.z; p[7] = (__bf16)v1.w;
        *reinterpret_cast<bf16x8*>(&e_lds[row * DIM + ch * 8]) = p;
    }
    en_lds[t] = enorm[t];
    en_lds[t + BLOCK] = enorm[t + BLOCK];
    __syncthreads();

    // ---- scoring loop over 32 code-groups of 16
    float best[2][4];
    int bidx[2][4];
#pragma unroll
    for (int mf = 0; mf < 2; ++mf)
#pragma unroll
        for (int r = 0; r < 4; ++r) { best[mf][r] = 3.4e38f; bidx[mf][r] = 0; }

    const int swz = l15 & 7;
#pragma unroll 4
    for (int nf = 0; nf < 32; ++nf) {
        const int n = nf * 16 + l15;
        bf16x8 b0 = *reinterpret_cast<const bf16x8*>(
            &e_lds[n * DIM + ((lq) ^ swz) * 8]);
        bf16x8 b1 = *reinterpret_cast<const bf16x8*>(
            &e_lds[n * DIM + ((lq + 4) ^ swz) * 8]);
        float en = en_lds[n];
        f32x4 acc0 = {0.f, 0.f, 0.f, 0.f};
        f32x4 acc1 = {0.f, 0.f, 0.f, 0.f};
        acc0 = __builtin_amdgcn_mfma_f32_16x16x32_bf16(afrag[0][0], b0, acc0, 0, 0, 0);
        acc0 = __builtin_amdgcn_mfma_f32_16x16x32_bf16(afrag[0][1], b1, acc0, 0, 0, 0);
        acc1 = __builtin_amdgcn_mfma_f32_16x16x32_bf16(afrag[1][0], b0, acc1, 0, 0, 0);
        acc1 = __builtin_amdgcn_mfma_f32_16x16x32_bf16(afrag[1][1], b1, acc1, 0, 0, 0);
#pragma unroll
        for (int r = 0; r < 4; ++r) {
            float s0 = fmaf(-2.f, acc0[r], en);
            float s1 = fmaf(-2.f, acc1[r], en);
            if (s0 < best[0][r]) { best[0][r] = s0; bidx[0][r] = n; }
            if (s1 < best[1][r]) { best[1][r] = s1; bidx[1][r] = n; }
        }
    }

    // ---- cross-lane argmin over the 16 col-lanes (tie -> smaller idx)
#pragma unroll
    for (int off = 1; off < 16; off <<= 1) {
#pragma unroll
        for (int mf = 0; mf < 2; ++mf) {
#pragma unroll
            for (int r = 0; r < 4; ++r) {
                float ob = __shfl_xor(best[mf][r], off, 64);
                int oi = __shfl_xor(bidx[mf][r], off, 64);
                if (ob < best[mf][r] ||
                    (ob == best[mf][r] && oi < bidx[mf][r])) {
                    best[mf][r] = ob;
                    bidx[mf][r] = oi;
                }
            }
        }
    }
    if (l15 == 0) {
#pragma unroll
        for (int mf = 0; mf < 2; ++mf)
#pragma unroll
            for (int r = 0; r < 4; ++r)
                bestk_lds[wid * 32 + mf * 16 + lq * 4 + r] = bidx[mf][r];
    }
    __syncthreads();

    // ---- gather (exact fp32) + output write + loss partial, coalesced
    float lsum = 0.f;
    const float4* latb = reinterpret_cast<const float4*>(lat + blockrow * DIM);
    float4* outb = reinterpret_cast<float4*>(outq + blockrow * DIM);
#pragma unroll
    for (int j = 0; j < 8; ++j) {
        int c = t + j * BLOCK;  // float4 chunk in tile (2048 total)
        int row = c >> 4;
        int k = bestk_lds[row];
        float4 e4 = reinterpret_cast<const float4*>(emb + k * DIM)[c & 15];
        float4 x4 = latb[c];
        outb[c] = e4;
        float d0 = e4.x - x4.x, d1 = e4.y - x4.y;
        float d2 = e4.z - x4.z, d3 = e4.w - x4.w;
        lsum = fmaf(d0, d0, lsum);
        lsum = fmaf(d1, d1, lsum);
        lsum = fmaf(d2, d2, lsum);
        lsum = fmaf(d3, d3, lsum);
    }

    // ---- deterministic block reduce
#pragma unroll
    for (int off = 32; off > 0; off >>= 1)
        lsum += __shfl_down(lsum, off, 64);
    if ((t & 63) == 0) wsum_lds[wid] = lsum;
    __syncthreads();
    if (t == 0) {
        float s = 0.f;
#pragma unroll
        for (int w = 0; w < BLOCK / 64; ++w) s += wsum_lds[w];
        partials[blockIdx.x] = s;
    }
}

// ---------------------------------------------------------------------------
// Kernel C: reduce partials -> vq_loss = 1.25 * mean((q-x)^2)
// ---------------------------------------------------------------------------
__global__ void vq_loss_kernel(const float* __restrict__ partials,
                               float* __restrict__ loss) {
    float s = 0.f;
    for (int i = threadIdx.x; i < NBLK; i += BLOCK) s += partials[i];
#pragma unroll
    for (int off = 32; off > 0; off >>= 1)
        s += __shfl_down(s, off, 64);
    __shared__ float wsum[BLOCK / 64];
    const int lane = threadIdx.x & 63;
    const int wid = threadIdx.x >> 6;
    if (lane == 0) wsum[wid] = s;
    __syncthreads();
    if (threadIdx.x == 0) {
        float tsum = 0.f;
#pragma unroll
        for (int w = 0; w < BLOCK / 64; ++w) tsum += wsum[w];
        loss[0] = 1.25f * (tsum / (float)((size_t)NROWS * DIM));
    }
}

// ---------------------------------------------------------------------------
extern "C" void kernel_launch(void* const* d_in, const int* in_sizes, int n_in,
                              void* d_out, int out_size, void* d_ws, size_t ws_size,
                              hipStream_t stream) {
    const float* lat = (const float*)d_in[0];   // [B,S,D] fp32
    const float* emb = (const float*)d_in[1];   // [K,D]   fp32
    float* outq = (float*)d_out;                              // output 0
    float* loss = (float*)d_out + (size_t)NROWS * DIM;        // output 1

    float* enorm = (float*)d_ws;                 // [512]
    float* partials = (float*)d_ws + KCODES;     // [2048]

    vq_enorm_kernel<<<(KCODES + 255) / 256, 256, 0, stream>>>(emb, enorm);
    vq_mfma_kernel<<<NBLK, BLOCK, 0, stream>>>(lat, emb, enorm, outq, partials);
    vq_loss_kernel<<<1, BLOCK, 0, stream>>>(partials, loss);
}

// Round 3
// 54.876 us; speedup vs baseline: 8.7455x; 1.1496x over previous
//
#include <hip/hip_runtime.h>
#include <math.h>
#include <stdint.h>

#define KCODES 512
#define DIM 64
#define NROWS (64 * 4096)     // B*S = 262144
#define BM 256                // rows per block
#define BLOCK 512             // 8 waves
#define NBLK (NROWS / BM)     // 1024

typedef __bf16 bf16x8 __attribute__((ext_vector_type(8)));
typedef float f32x4 __attribute__((ext_vector_type(4)));

typedef __attribute__((address_space(3))) uint32_t* lds_ptr_t;
typedef const __attribute__((address_space(1))) uint32_t* glb_ptr_t;

// ---------------------------------------------------------------------------
// Kernel A (prep, runs once): per code k
//   enorm[k] = ||e_k||^2 (exact fp32)
//   ebf[k*64 + (j ^ (k&7))*8 .. +7] = bf16(e_k[j*8 .. j*8+7])   (pre-swizzled)
// The swizzle is the SAME involution the main kernel's ds_read applies, so
// linear global_load_lds staging + swizzled read reconstruct E correctly.
// ---------------------------------------------------------------------------
__global__ void vq_prep_kernel(const float* __restrict__ emb,
                               float* __restrict__ enorm,
                               __bf16* __restrict__ ebf) {
    int k = blockIdx.x * blockDim.x + threadIdx.x;
    if (k >= KCODES) return;
    const float4* e4 = reinterpret_cast<const float4*>(emb + k * DIM);
    float s0 = 0.f, s1 = 0.f, s2 = 0.f, s3 = 0.f;
#pragma unroll
    for (int j = 0; j < 8; ++j) {          // 8 chunks of 8 elems
        float4 v0 = e4[j * 2];
        float4 v1 = e4[j * 2 + 1];
        s0 = fmaf(v0.x, v0.x, s0); s1 = fmaf(v0.y, v0.y, s1);
        s2 = fmaf(v0.z, v0.z, s2); s3 = fmaf(v0.w, v0.w, s3);
        s0 = fmaf(v1.x, v1.x, s0); s1 = fmaf(v1.y, v1.y, s1);
        s2 = fmaf(v1.z, v1.z, s2); s3 = fmaf(v1.w, v1.w, s3);
        bf16x8 p;
        p[0] = (__bf16)v0.x; p[1] = (__bf16)v0.y;
        p[2] = (__bf16)v0.z; p[3] = (__bf16)v0.w;
        p[4] = (__bf16)v1.x; p[5] = (__bf16)v1.y;
        p[6] = (__bf16)v1.z; p[7] = (__bf16)v1.w;
        *reinterpret_cast<bf16x8*>(&ebf[k * DIM + (j ^ (k & 7)) * 8]) = p;
    }
    enorm[k] = (s0 + s1) + (s2 + s3);
}

// ---------------------------------------------------------------------------
// Kernel B: MFMA scoring + argmin + gather + loss partial.
//   scores[m][n] = enorm[n] - 2 * x_m . e_n   (bf16 MFMA, fp32 accum)
//   C/D layout: col(n) = lane&15, row(m) = (lane>>4)*4 + r  [m89/m91]
// 8 waves x 32 rows = 256 rows per block; E (bf16, swizzled) staged via
// global_load_lds (linear dest, pre-swizzled source).
// ---------------------------------------------------------------------------
__launch_bounds__(BLOCK, 4)
__global__ void vq_mfma_kernel(const float* __restrict__ lat,
                               const float* __restrict__ emb,
                               const float* __restrict__ enorm,
                               const __bf16* __restrict__ ebf,
                               float* __restrict__ outq,
                               float* __restrict__ partials) {
    __shared__ __align__(16) __bf16 e_lds[KCODES * DIM];  // 64 KB, swizzled
    __shared__ float en_lds[KCODES];
    __shared__ int bestk_lds[BM];
    __shared__ float wsum_lds[BLOCK / 64];

    const int t = threadIdx.x;
    const int lane = t & 63, wid = t >> 6;
    const int l15 = lane & 15, lq = lane >> 4;
    const size_t blockrow = (size_t)blockIdx.x * BM;

    // ---- stage E: bf16 ws -> LDS, 16B per lane, linear, no VALU.
    // 4096 chunks of 16B; 8 per thread.
#pragma unroll
    for (int i = 0; i < 8; ++i) {
        int c = t + i * BLOCK;
        __builtin_amdgcn_global_load_lds(
            (glb_ptr_t)(const void*)(ebf + c * 8),
            (lds_ptr_t)(void*)(&e_lds[c * 8]), 16, 0, 0);
    }

    // ---- A fragments: global -> reg, convert to bf16 (overlaps staging).
    bf16x8 afrag[2][2];
#pragma unroll
    for (int mf = 0; mf < 2; ++mf) {
#pragma unroll
        for (int ks = 0; ks < 2; ++ks) {
            const float* xp =
                lat + (blockrow + wid * 32 + mf * 16 + l15) * DIM + ks * 32 + lq * 8;
            float4 v0 = reinterpret_cast<const float4*>(xp)[0];
            float4 v1 = reinterpret_cast<const float4*>(xp)[1];
            bf16x8 a;
            a[0] = (__bf16)v0.x; a[1] = (__bf16)v0.y;
            a[2] = (__bf16)v0.z; a[3] = (__bf16)v0.w;
            a[4] = (__bf16)v1.x; a[5] = (__bf16)v1.y;
            a[6] = (__bf16)v1.z; a[7] = (__bf16)v1.w;
            afrag[mf][ks] = a;
        }
    }
    en_lds[t] = enorm[t];
    __syncthreads();

    // ---- scoring loop over 32 code-groups of 16
    float best[2][4];
    int bidx[2][4];
#pragma unroll
    for (int mf = 0; mf < 2; ++mf)
#pragma unroll
        for (int r = 0; r < 4; ++r) { best[mf][r] = 3.4e38f; bidx[mf][r] = 0; }

    const int swz = l15 & 7;
#pragma unroll 4
    for (int nf = 0; nf < 32; ++nf) {
        const int n = nf * 16 + l15;
        bf16x8 b0 = *reinterpret_cast<const bf16x8*>(
            &e_lds[n * DIM + (lq ^ swz) * 8]);
        bf16x8 b1 = *reinterpret_cast<const bf16x8*>(
            &e_lds[n * DIM + ((lq + 4) ^ swz) * 8]);
        float en = en_lds[n];
        f32x4 acc0 = {0.f, 0.f, 0.f, 0.f};
        f32x4 acc1 = {0.f, 0.f, 0.f, 0.f};
        acc0 = __builtin_amdgcn_mfma_f32_16x16x32_bf16(afrag[0][0], b0, acc0, 0, 0, 0);
        acc0 = __builtin_amdgcn_mfma_f32_16x16x32_bf16(afrag[0][1], b1, acc0, 0, 0, 0);
        acc1 = __builtin_amdgcn_mfma_f32_16x16x32_bf16(afrag[1][0], b0, acc1, 0, 0, 0);
        acc1 = __builtin_amdgcn_mfma_f32_16x16x32_bf16(afrag[1][1], b1, acc1, 0, 0, 0);
#pragma unroll
        for (int r = 0; r < 4; ++r) {
            float s0 = fmaf(-2.f, acc0[r], en);
            float s1 = fmaf(-2.f, acc1[r], en);
            if (s0 < best[0][r]) { best[0][r] = s0; bidx[0][r] = n; }
            if (s1 < best[1][r]) { best[1][r] = s1; bidx[1][r] = n; }
        }
    }

    // ---- cross-lane argmin over the 16 col-lanes (tie -> smaller idx)
#pragma unroll
    for (int off = 1; off < 16; off <<= 1) {
#pragma unroll
        for (int mf = 0; mf < 2; ++mf) {
#pragma unroll
            for (int r = 0; r < 4; ++r) {
                float ob = __shfl_xor(best[mf][r], off, 64);
                int oi = __shfl_xor(bidx[mf][r], off, 64);
                if (ob < best[mf][r] ||
                    (ob == best[mf][r] && oi < bidx[mf][r])) {
                    best[mf][r] = ob;
                    bidx[mf][r] = oi;
                }
            }
        }
    }
    if (l15 == 0) {
#pragma unroll
        for (int mf = 0; mf < 2; ++mf)
#pragma unroll
            for (int r = 0; r < 4; ++r)
                bestk_lds[wid * 32 + mf * 16 + lq * 4 + r] = bidx[mf][r];
    }
    __syncthreads();

    // ---- gather (exact fp32) + output write + loss partial, coalesced
    float lsum = 0.f;
    const float4* latb = reinterpret_cast<const float4*>(lat + blockrow * DIM);
    float4* outb = reinterpret_cast<float4*>(outq + blockrow * DIM);
#pragma unroll
    for (int j = 0; j < 8; ++j) {
        int c = t + j * BLOCK;  // float4 chunk in tile (4096 total)
        int row = c >> 4;
        int k = bestk_lds[row];
        float4 e4 = reinterpret_cast<const float4*>(emb + k * DIM)[c & 15];
        float4 x4 = latb[c];
        outb[c] = e4;
        float d0 = e4.x - x4.x, d1 = e4.y - x4.y;
        float d2 = e4.z - x4.z, d3 = e4.w - x4.w;
        lsum = fmaf(d0, d0, lsum);
        lsum = fmaf(d1, d1, lsum);
        lsum = fmaf(d2, d2, lsum);
        lsum = fmaf(d3, d3, lsum);
    }

    // ---- deterministic block reduce
#pragma unroll
    for (int off = 32; off > 0; off >>= 1)
        lsum += __shfl_down(lsum, off, 64);
    if (lane == 0) wsum_lds[wid] = lsum;
    __syncthreads();
    if (t == 0) {
        float s = 0.f;
#pragma unroll
        for (int w = 0; w < BLOCK / 64; ++w) s += wsum_lds[w];
        partials[blockIdx.x] = s;
    }
}

// ---------------------------------------------------------------------------
// Kernel C: reduce partials -> vq_loss = 1.25 * mean((q-x)^2)
// ---------------------------------------------------------------------------
__global__ void vq_loss_kernel(const float* __restrict__ partials,
                               float* __restrict__ loss) {
    float s = 0.f;
    for (int i = threadIdx.x; i < NBLK; i += 256) s += partials[i];
#pragma unroll
    for (int off = 32; off > 0; off >>= 1)
        s += __shfl_down(s, off, 64);
    __shared__ float wsum[4];
    const int lane = threadIdx.x & 63;
    const int wid = threadIdx.x >> 6;
    if (lane == 0) wsum[wid] = s;
    __syncthreads();
    if (threadIdx.x == 0) {
        float tsum = 0.f;
#pragma unroll
        for (int w = 0; w < 4; ++w) tsum += wsum[w];
        loss[0] = 1.25f * (tsum / (float)((size_t)NROWS * DIM));
    }
}

// ---------------------------------------------------------------------------
extern "C" void kernel_launch(void* const* d_in, const int* in_sizes, int n_in,
                              void* d_out, int out_size, void* d_ws, size_t ws_size,
                              hipStream_t stream) {
    const float* lat = (const float*)d_in[0];   // [B,S,D] fp32
    const float* emb = (const float*)d_in[1];   // [K,D]   fp32
    float* outq = (float*)d_out;                              // output 0
    float* loss = (float*)d_out + (size_t)NROWS * DIM;        // output 1

    // ws layout (bytes): [0,2048) enorm f32[512]
    //                    [2048, 67584) ebf bf16[512*64] (pre-swizzled)
    //                    [67584, 71680) partials f32[1024]
    float* enorm = (float*)d_ws;
    __bf16* ebf = (__bf16*)((char*)d_ws + 2048);
    float* partials = (float*)((char*)d_ws + 67584);

    vq_prep_kernel<<<2, 256, 0, stream>>>(emb, enorm, ebf);
    vq_mfma_kernel<<<NBLK, BLOCK, 0, stream>>>(lat, emb, enorm, ebf, outq, partials);
    vq_loss_kernel<<<1, 256, 0, stream>>>(partials, loss);
}

// Round 4
// 47.826 us; speedup vs baseline: 10.0347x; 1.1474x over previous
//
#include <hip/hip_runtime.h>
#include <math.h>
#include <stdint.h>

#define KCODES 512
#define DIM 64
#define NROWS (64 * 4096)     // B*S = 262144
#define BM 256                // rows per block
#define BLOCK 512             // 8 waves
#define NBLK (NROWS / BM)     // 1024
#define HALFK 256             // codes staged per pass

typedef __bf16 bf16x8 __attribute__((ext_vector_type(8)));
typedef float f32x4 __attribute__((ext_vector_type(4)));

typedef __attribute__((address_space(3))) uint32_t* lds_ptr_t;
typedef const __attribute__((address_space(1))) uint32_t* glb_ptr_t;

// ---------------------------------------------------------------------------
// Kernel A (prep, runs once): per code k
//   en1[k] = 1.0 + ||e_k||^2                      (exact fp32)
//   ebf[k*64 + (j ^ (k&7))*8 .. +7] = bf16(-2 * e_k[j*8..])  (pre-swizzled,
//   pre-scaled by -2 so the MFMA emits the score directly)
// ---------------------------------------------------------------------------
__global__ void vq_prep_kernel(const float* __restrict__ emb,
                               float* __restrict__ en1,
                               __bf16* __restrict__ ebf) {
    int k = blockIdx.x * blockDim.x + threadIdx.x;
    if (k >= KCODES) return;
    const float4* e4 = reinterpret_cast<const float4*>(emb + k * DIM);
    float s0 = 0.f, s1 = 0.f, s2 = 0.f, s3 = 0.f;
#pragma unroll
    for (int j = 0; j < 8; ++j) {          // 8 chunks of 8 elems
        float4 v0 = e4[j * 2];
        float4 v1 = e4[j * 2 + 1];
        s0 = fmaf(v0.x, v0.x, s0); s1 = fmaf(v0.y, v0.y, s1);
        s2 = fmaf(v0.z, v0.z, s2); s3 = fmaf(v0.w, v0.w, s3);
        s0 = fmaf(v1.x, v1.x, s0); s1 = fmaf(v1.y, v1.y, s1);
        s2 = fmaf(v1.z, v1.z, s2); s3 = fmaf(v1.w, v1.w, s3);
        bf16x8 p;
        p[0] = (__bf16)(-2.f * v0.x); p[1] = (__bf16)(-2.f * v0.y);
        p[2] = (__bf16)(-2.f * v0.z); p[3] = (__bf16)(-2.f * v0.w);
        p[4] = (__bf16)(-2.f * v1.x); p[5] = (__bf16)(-2.f * v1.y);
        p[6] = (__bf16)(-2.f * v1.z); p[7] = (__bf16)(-2.f * v1.w);
        *reinterpret_cast<bf16x8*>(&ebf[k * DIM + (j ^ (k & 7)) * 8]) = p;
    }
    en1[k] = 1.0f + (s0 + s1) + (s2 + s3);
}

// ---------------------------------------------------------------------------
// Kernel B: MFMA scoring + packed-key argmin + gather + loss partial.
//   score_k(+1) = en1[k] + x . (-2 e_k)   via acc-init = en1, bf16 MFMA
//   score+1 in [~0.6, 1.6] > 0  => as_uint order-preserving
//   key = (as_uint(score) & ~511) | k ; umin reduce; tie -> smaller k.
// E staged in TWO 256-code passes through one 32 KB LDS buffer -> 4 blk/CU.
// ---------------------------------------------------------------------------
__launch_bounds__(BLOCK, 8)
__global__ void vq_mfma_kernel(const float* __restrict__ lat,
                               const float* __restrict__ emb,
                               const float* __restrict__ en1,
                               const __bf16* __restrict__ ebf,
                               float* __restrict__ outq,
                               float* __restrict__ partials) {
    __shared__ __align__(16) __bf16 e_lds[HALFK * DIM];   // 32 KB, swizzled
    __shared__ float en_lds[KCODES];                      // 2 KB
    __shared__ int bestk_lds[BM];                         // 1 KB
    __shared__ float wsum_lds[BLOCK / 64];

    const int t = threadIdx.x;
    const int lane = t & 63, wid = t >> 6;
    const int l15 = lane & 15, lq = lane >> 4;
    const int swz = l15 & 7;
    const size_t blockrow = (size_t)blockIdx.x * BM;

    // ---- stage E half 0: bf16 ws -> LDS, 16B/lane, linear dest.
#pragma unroll
    for (int i = 0; i < 4; ++i) {
        int c = t + i * BLOCK;            // 16B chunk id, 0..2047
        __builtin_amdgcn_global_load_lds(
            (glb_ptr_t)(const void*)(ebf + c * 8),
            (lds_ptr_t)(void*)(&e_lds[c * 8]), 16, 0, 0);
    }

    // ---- A fragments: global -> reg, convert to bf16 (overlaps staging).
    bf16x8 afrag[2][2];
#pragma unroll
    for (int mf = 0; mf < 2; ++mf) {
#pragma unroll
        for (int ks = 0; ks < 2; ++ks) {
            const float* xp =
                lat + (blockrow + wid * 32 + mf * 16 + l15) * DIM + ks * 32 + lq * 8;
            float4 v0 = reinterpret_cast<const float4*>(xp)[0];
            float4 v1 = reinterpret_cast<const float4*>(xp)[1];
            bf16x8 a;
            a[0] = (__bf16)v0.x; a[1] = (__bf16)v0.y;
            a[2] = (__bf16)v0.z; a[3] = (__bf16)v0.w;
            a[4] = (__bf16)v1.x; a[5] = (__bf16)v1.y;
            a[6] = (__bf16)v1.z; a[7] = (__bf16)v1.w;
            afrag[mf][ks] = a;
        }
    }
    en_lds[t] = en1[t];   // t covers 0..511 = all KCODES
    __syncthreads();      // drains vmcnt -> half0 + en ready

    uint32_t best[2][4];
#pragma unroll
    for (int mf = 0; mf < 2; ++mf)
#pragma unroll
        for (int r = 0; r < 4; ++r) best[mf][r] = 0xFFFFFFFFu;

    // ================= pass over half h of the codebook =================
#pragma unroll
    for (int h = 0; h < 2; ++h) {
        if (h == 1) {
            __syncthreads();   // everyone done reading half0
#pragma unroll
            for (int i = 0; i < 4; ++i) {
                int c = t + i * BLOCK;
                __builtin_amdgcn_global_load_lds(
                    (glb_ptr_t)(const void*)(ebf + HALFK * DIM + c * 8),
                    (lds_ptr_t)(void*)(&e_lds[c * 8]), 16, 0, 0);
            }
            __syncthreads();   // drains vmcnt -> half1 ready
        }
#pragma unroll 4
        for (int nf = 0; nf < 16; ++nf) {
            const int n = h * HALFK + nf * 16 + l15;
            const int lrow = n & (HALFK - 1);
            bf16x8 b0 = *reinterpret_cast<const bf16x8*>(
                &e_lds[lrow * DIM + (lq ^ swz) * 8]);
            bf16x8 b1 = *reinterpret_cast<const bf16x8*>(
                &e_lds[lrow * DIM + ((lq + 4) ^ swz) * 8]);
            float en = en_lds[n];
            f32x4 acc0 = {en, en, en, en};
            f32x4 acc1 = {en, en, en, en};
            acc0 = __builtin_amdgcn_mfma_f32_16x16x32_bf16(afrag[0][0], b0, acc0, 0, 0, 0);
            acc0 = __builtin_amdgcn_mfma_f32_16x16x32_bf16(afrag[0][1], b1, acc0, 0, 0, 0);
            acc1 = __builtin_amdgcn_mfma_f32_16x16x32_bf16(afrag[1][0], b0, acc1, 0, 0, 0);
            acc1 = __builtin_amdgcn_mfma_f32_16x16x32_bf16(afrag[1][1], b1, acc1, 0, 0, 0);
            const uint32_t nn = (uint32_t)n;
#pragma unroll
            for (int r = 0; r < 4; ++r) {
                uint32_t k0 = (__float_as_uint(acc0[r]) & 0xFFFFFE00u) | nn;
                uint32_t k1 = (__float_as_uint(acc1[r]) & 0xFFFFFE00u) | nn;
                best[0][r] = min(best[0][r], k0);
                best[1][r] = min(best[1][r], k1);
            }
        }
    }

    // ---- cross-lane umin over the 16 col-lanes (tie -> smaller idx, free)
#pragma unroll
    for (int off = 1; off < 16; off <<= 1) {
#pragma unroll
        for (int mf = 0; mf < 2; ++mf)
#pragma unroll
            for (int r = 0; r < 4; ++r) {
                uint32_t o = (uint32_t)__shfl_xor((int)best[mf][r], off, 64);
                best[mf][r] = min(best[mf][r], o);
            }
    }
    if (l15 == 0) {
#pragma unroll
        for (int mf = 0; mf < 2; ++mf)
#pragma unroll
            for (int r = 0; r < 4; ++r)
                bestk_lds[wid * 32 + mf * 16 + lq * 4 + r] =
                    (int)(best[mf][r] & 511u);
    }
    __syncthreads();

    // ---- gather (exact fp32) + output write + loss partial, coalesced
    float lsum = 0.f;
    const float4* latb = reinterpret_cast<const float4*>(lat + blockrow * DIM);
    float4* outb = reinterpret_cast<float4*>(outq + blockrow * DIM);
#pragma unroll
    for (int j = 0; j < 8; ++j) {
        int c = t + j * BLOCK;  // float4 chunk in tile (4096 total)
        int row = c >> 4;
        int k = bestk_lds[row];
        float4 e4 = reinterpret_cast<const float4*>(emb + k * DIM)[c & 15];
        float4 x4 = latb[c];
        outb[c] = e4;
        float d0 = e4.x - x4.x, d1 = e4.y - x4.y;
        float d2 = e4.z - x4.z, d3 = e4.w - x4.w;
        lsum = fmaf(d0, d0, lsum);
        lsum = fmaf(d1, d1, lsum);
        lsum = fmaf(d2, d2, lsum);
        lsum = fmaf(d3, d3, lsum);
    }

    // ---- deterministic block reduce
#pragma unroll
    for (int off = 32; off > 0; off >>= 1)
        lsum += __shfl_down(lsum, off, 64);
    if (lane == 0) wsum_lds[wid] = lsum;
    __syncthreads();
    if (t == 0) {
        float s = 0.f;
#pragma unroll
        for (int w = 0; w < BLOCK / 64; ++w) s += wsum_lds[w];
        partials[blockIdx.x] = s;
    }
}

// ---------------------------------------------------------------------------
// Kernel C: reduce partials -> vq_loss = 1.25 * mean((q-x)^2)
// ---------------------------------------------------------------------------
__global__ void vq_loss_kernel(const float* __restrict__ partials,
                               float* __restrict__ loss) {
    float s = 0.f;
    for (int i = threadIdx.x; i < NBLK; i += 256) s += partials[i];
#pragma unroll
    for (int off = 32; off > 0; off >>= 1)
        s += __shfl_down(s, off, 64);
    __shared__ float wsum[4];
    const int lane = threadIdx.x & 63;
    const int wid = threadIdx.x >> 6;
    if (lane == 0) wsum[wid] = s;
    __syncthreads();
    if (threadIdx.x == 0) {
        float tsum = 0.f;
#pragma unroll
        for (int w = 0; w < 4; ++w) tsum += wsum[w];
        loss[0] = 1.25f * (tsum / (float)((size_t)NROWS * DIM));
    }
}

// ---------------------------------------------------------------------------
extern "C" void kernel_launch(void* const* d_in, const int* in_sizes, int n_in,
                              void* d_out, int out_size, void* d_ws, size_t ws_size,
                              hipStream_t stream) {
    const float* lat = (const float*)d_in[0];   // [B,S,D] fp32
    const float* emb = (const float*)d_in[1];   // [K,D]   fp32
    float* outq = (float*)d_out;                              // output 0
    float* loss = (float*)d_out + (size_t)NROWS * DIM;        // output 1

    // ws layout (bytes): [0,2048) en1 f32[512]
    //                    [2048, 67584) ebf bf16[512*64] (pre-swizzled, x -2)
    //                    [67584, 71680) partials f32[1024]
    float* en1 = (float*)d_ws;
    __bf16* ebf = (__bf16*)((char*)d_ws + 2048);
    float* partials = (float*)((char*)d_ws + 67584);

    vq_prep_kernel<<<2, 256, 0, stream>>>(emb, en1, ebf);
    vq_mfma_kernel<<<NBLK, BLOCK, 0, stream>>>(lat, emb, en1, ebf, outq, partials);
    vq_loss_kernel<<<1, 256, 0, stream>>>(partials, loss);
}